// Round 6
// baseline (222.339 us; speedup 1.0000x reference)
//
#include <hip/hip_runtime.h>
#include <cstdint>
#include <math.h>

#define NB 4
#define NN 512
#define DH 128
#define NHEADS 8
#define NHID 16
#define ITILE 64
#define SENTINEL -1e30f

// ---- fully-fused GAT layer v2: scalar-pipe proj + flash attention ----
// 3 dispatches total. Block (b, hh, it): 512 threads, 146 KB LDS, 1 block/CU.
//
// proj phase (rewritten this round): W never touches LDS. Each wave owns a
// uniform column-octet (coct = readfirstlane(t>>7)) so W reads are
// wave-uniform -> scalar s_load stream (SGPRs, constant cache); h is staged
// in LDS quarters [128][132] (pad-132 -> <=4-way read conflict). Thread
// (coct, rg=t&127) computes 1 row x 8 cols per quarter. This removes the
// previous 8192 broadcast ds_read_b128/CU (~20 us of 44.6) from the LDS pipe.
//
// attn phase: byte-identical math to the verified R5 kernel (absmax 0.0):
// f-major planes, factored lrelu score, two-pass in-register softmax,
// swizzled LDS merge. Layer 0 packs adj bitmasks; layer 1 zeroes out[].
__global__ __launch_bounds__(512, 1) void gat_layer(
    const int lay,
    const float* __restrict__ X, const float* __restrict__ hin,
    float* __restrict__ hout,
    const float* __restrict__ Win,
    const float* __restrict__ WlL, const float* __restrict__ WrL,
    const float* __restrict__ a_vec, const float* __restrict__ Wout,
    float* __restrict__ out, uint32_t* __restrict__ adjb,
    const int* __restrict__ adj)
{
    __shared__ __align__(16) float smem[36512];   // 146,048 B -> 1 block/CU
    float* s_h   = smem;                  // [128][132] h quarter (proj)
    float* s_acc = smem;                  // alias (attn merge scratch, 16384)
    float* Sgl_f = smem + 16896;          // [4][512] float4 f-major gl
    float* Sgr_f = smem + 25088;          // [4][512] float4 f-major gr
    float* s_dgl = smem + 33280;          // [512]
    float* s_dgr = smem + 33792;          // [512]
    float* s_m   = smem + 34304;          // [16][65]
    float* s_l   = smem + 35344;          // [16][65]
    float* s_M   = smem + 36384;          // [64]
    float* s_inv = smem + 36448;          // [64]
    float4* Sgl  = (float4*)Sgl_f;
    float4* Sgr  = (float4*)Sgr_f;

    const int blk = blockIdx.x;           // 256 = ((b*8+hh)*8) + it
    const int it  = blk & 7;
    const int bh  = blk >> 3;
    const int b   = bh >> 3;
    const int hh  = bh & 7;
    const int i0  = it * ITILE;
    const int t   = threadIdx.x;
    const int il  = t & 31;
    const int js  = t >> 5;               // [0,16)
    const int r0  = i0 + il;
    const int r1  = r0 + 32;

    float a[16];
#pragma unroll
    for (int q = 0; q < 4; ++q) {
        const float4 v = ((const float4*)a_vec)[q];
        a[4*q+0] = v.x; a[4*q+1] = v.y; a[4*q+2] = v.z; a[4*q+3] = v.w;
    }

    // ---- masks: layer 0 packs from adj (and stores for reuse); else load ----
    uint32_t mask0, mask1;
    if (lay == 0) {
        const int4* p0 = (const int4*)(adj + ((size_t)(b * NN + r0)) * NN + js * 32);
        const int4* p1 = (const int4*)(adj + ((size_t)(b * NN + r1)) * NN + js * 32);
        uint32_t m0 = 0, m1 = 0;
#pragma unroll
        for (int c = 0; c < 8; ++c) {
            const int4 v0 = p0[c], v1 = p1[c];
            m0 |= (v0.x != 0 ? 1u : 0u) << (c * 4 + 0);
            m0 |= (v0.y != 0 ? 1u : 0u) << (c * 4 + 1);
            m0 |= (v0.z != 0 ? 1u : 0u) << (c * 4 + 2);
            m0 |= (v0.w != 0 ? 1u : 0u) << (c * 4 + 3);
            m1 |= (v1.x != 0 ? 1u : 0u) << (c * 4 + 0);
            m1 |= (v1.y != 0 ? 1u : 0u) << (c * 4 + 1);
            m1 |= (v1.z != 0 ? 1u : 0u) << (c * 4 + 2);
            m1 |= (v1.w != 0 ? 1u : 0u) << (c * 4 + 3);
        }
        mask0 = m0; mask1 = m1;
        adjb[((size_t)(b * NN + r0)) * 16 + js] = m0;  // 8 hh-blocks same value: benign
        adjb[((size_t)(b * NN + r1)) * 16 + js] = m1;
    } else {
        mask0 = adjb[((size_t)(b * NN + r0)) * 16 + js];
        mask1 = adjb[((size_t)(b * NN + r1)) * 16 + js];
    }

    // ---- proj: 4 quarters of 128 rows; thread (coct, rg) -> 1 row x 8 cols ----
    const int coct = __builtin_amdgcn_readfirstlane(t >> 7);   // wave-uniform
    const int rg   = t & 127;
    // uniform W column base: coct 0/1 -> Wl cols 0-7/8-15, 2/3 -> Wr cols 0-7/8-15
    const float* Wbase = ((coct < 2) ? WlL : WrL) + hh * NHID + (coct & 1) * 8;

#pragma unroll 1
    for (int qt = 0; qt < 4; ++qt) {
        const int rbase = qt * 128;
        __syncthreads();                 // previous quarter's s_h reads done
        // stage h quarter -> s_h[row][132]
        for (int i = t; i < 128 * 32; i += 512) {
            const int row = i >> 5, q = i & 31;
            float4 h4;
            if (lay == 0) {
                const float x0 = X[(b * NN + rbase + row) * 2 + 0];
                const float x1 = X[(b * NN + rbase + row) * 2 + 1];
                const float4 w0 = *(const float4*)&Win[q * 4];
                const float4 w1 = *(const float4*)&Win[DH + q * 4];
                h4.x = x0 * w0.x + x1 * w1.x;
                h4.y = x0 * w0.y + x1 * w1.y;
                h4.z = x0 * w0.z + x1 * w1.z;
                h4.w = x0 * w0.w + x1 * w1.w;
            } else {
                h4 = *(const float4*)&hin[((size_t)(b * NN + rbase + row)) * DH + q * 4];
            }
            *(float4*)&s_h[row * 132 + q * 4] = h4;
        }
        __syncthreads();
        // compute: acc[8] over k, W via uniform scalar loads
        float acc[8] = {};
#pragma unroll 2
        for (int k = 0; k < DH; k += 4) {
            const float4 hv = *(const float4*)&s_h[rg * 132 + k];
            const float* hp = &hv.x;
#pragma unroll
            for (int kk = 0; kk < 4; ++kk) {
                const float hk = hp[kk];
                const float* wr = Wbase + (k + kk) * DH;   // uniform -> s_load
#pragma unroll
                for (int c = 0; c < 8; ++c)
                    acc[c] = fmaf(hk, wr[c], acc[c]);
            }
        }
        {   // write f-major plane slice (lane-consecutive rows: conflict-free)
            float4 v0, v1;
            v0.x = acc[0]; v0.y = acc[1]; v0.z = acc[2]; v0.w = acc[3];
            v1.x = acc[4]; v1.y = acc[5]; v1.z = acc[6]; v1.w = acc[7];
            float4* Sg = (coct < 2) ? Sgl : Sgr;
            const int q0 = (coct & 1) * 2;
            Sg[q0 * 512       + rbase + rg] = v0;
            Sg[(q0 + 1) * 512 + rbase + rg] = v1;
        }
    }
    __syncthreads();                     // planes complete

    {   // dgl[t] = a . gl[t], dgr[t] = a . gr[t] (lane-consecutive reads)
        float dl = 0.f, dr = 0.f;
#pragma unroll
        for (int q = 0; q < 4; ++q) {
            const float4 vl = Sgl[q * 512 + t];
            const float4 vr = Sgr[q * 512 + t];
            dl = fmaf(a[4*q+0], vl.x, dl); dl = fmaf(a[4*q+1], vl.y, dl);
            dl = fmaf(a[4*q+2], vl.z, dl); dl = fmaf(a[4*q+3], vl.w, dl);
            dr = fmaf(a[4*q+0], vr.x, dr); dr = fmaf(a[4*q+1], vr.y, dr);
            dr = fmaf(a[4*q+2], vr.z, dr); dr = fmaf(a[4*q+3], vr.w, dr);
        }
        s_dgl[t] = dl;
        s_dgr[t] = dr;
    }
    __syncthreads();                     // dgl/dgr ready

    // ---- gri for own 2 rows ----
    float gri0[16], gri1[16];
#pragma unroll
    for (int q = 0; q < 4; ++q) {
        const float4 v0 = Sgr[q * 512 + r0];
        const float4 v1 = Sgr[q * 512 + r1];
        gri0[4*q+0] = v0.x; gri0[4*q+1] = v0.y; gri0[4*q+2] = v0.z; gri0[4*q+3] = v0.w;
        gri1[4*q+0] = v1.x; gri1[4*q+1] = v1.y; gri1[4*q+2] = v1.z; gri1[4*q+3] = v1.w;
    }

    // ---- pass 1: scores for 2 rows x 32 j ----
    const float c0 = 0.6f * s_dgr[r0];
    const float c1 = 0.6f * s_dgr[r1];
    const int jbase = js * 32;
    float sc0[32], sc1[32];
#pragma unroll
    for (int jj = 0; jj < 32; ++jj) {
        const int j = jbase + jj;
        const float dj = s_dgl[j];
        float s0 = 0.f, s1 = 0.f;
#pragma unroll
        for (int q = 0; q < 4; ++q) {
            const float4 g = Sgl[q * 512 + j];   // uniform j -> broadcast
            float v;
            v = g.x + gri0[4*q+0]; s0 = fmaf(a[4*q+0], fabsf(v), s0);
            v = g.y + gri0[4*q+1]; s0 = fmaf(a[4*q+1], fabsf(v), s0);
            v = g.z + gri0[4*q+2]; s0 = fmaf(a[4*q+2], fabsf(v), s0);
            v = g.w + gri0[4*q+3]; s0 = fmaf(a[4*q+3], fabsf(v), s0);
            v = g.x + gri1[4*q+0]; s1 = fmaf(a[4*q+0], fabsf(v), s1);
            v = g.y + gri1[4*q+1]; s1 = fmaf(a[4*q+1], fabsf(v), s1);
            v = g.z + gri1[4*q+2]; s1 = fmaf(a[4*q+2], fabsf(v), s1);
            v = g.w + gri1[4*q+3]; s1 = fmaf(a[4*q+3], fabsf(v), s1);
        }
        const float b0 = fmaf(0.6f, dj, c0);
        const float b1 = fmaf(0.6f, dj, c1);
        sc0[jj] = ((mask0 >> jj) & 1u) ? fmaf(0.4f, s0, b0) : SENTINEL;
        sc1[jj] = ((mask1 >> jj) & 1u) ? fmaf(0.4f, s1, b1) : SENTINEL;
    }

    // ---- in-register softmax (two-pass) ----
    float m0 = sc0[0], m1 = sc1[0];
#pragma unroll
    for (int jj = 1; jj < 32; ++jj) { m0 = fmaxf(m0, sc0[jj]); m1 = fmaxf(m1, sc1[jj]); }
    float l0 = 0.f, l1 = 0.f;
#pragma unroll
    for (int jj = 0; jj < 32; ++jj) {
        sc0[jj] = __expf(sc0[jj] - m0); l0 += sc0[jj];
        sc1[jj] = __expf(sc1[jj] - m1); l1 += sc1[jj];
    }
    s_m[js * 65 + il]      = m0;
    s_m[js * 65 + il + 32] = m1;
    s_l[js * 65 + il]      = l0;
    s_l[js * 65 + il + 32] = l1;

    // ---- pass 2: PV aggregation ----
    float acc0[16], acc1[16];
#pragma unroll
    for (int f = 0; f < 16; ++f) { acc0[f] = 0.f; acc1[f] = 0.f; }
#pragma unroll
    for (int jj = 0; jj < 32; ++jj) {
        const int j = jbase + jj;
        const float p0 = sc0[jj], p1 = sc1[jj];
#pragma unroll
        for (int q = 0; q < 4; ++q) {
            const float4 g = Sgr[q * 512 + j];   // broadcast
            acc0[4*q+0] = fmaf(p0, g.x, acc0[4*q+0]);
            acc0[4*q+1] = fmaf(p0, g.y, acc0[4*q+1]);
            acc0[4*q+2] = fmaf(p0, g.z, acc0[4*q+2]);
            acc0[4*q+3] = fmaf(p0, g.w, acc0[4*q+3]);
            acc1[4*q+0] = fmaf(p1, g.x, acc1[4*q+0]);
            acc1[4*q+1] = fmaf(p1, g.y, acc1[4*q+1]);
            acc1[4*q+2] = fmaf(p1, g.z, acc1[4*q+2]);
            acc1[4*q+3] = fmaf(p1, g.w, acc1[4*q+3]);
        }
    }
    __syncthreads();                     // retires plane reads + s_m/s_l writes

    if (t < 64) {                        // per-row global max + denom over 16 slices
        float M = SENTINEL;
#pragma unroll
        for (int k = 0; k < 16; ++k) M = fmaxf(M, s_m[k * 65 + t]);
        float L = 0.f;
#pragma unroll
        for (int k = 0; k < 16; ++k) L += s_l[k * 65 + t] * __expf(s_m[k * 65 + t] - M);
        s_M[t]   = M;
        s_inv[t] = 1.f / L;
    }
    __syncthreads();

    {   // scaled partials into aliased scratch; chunk-XOR swizzle
        const float k0 = __expf(m0 - s_M[il])      * s_inv[il];
        const float k1 = __expf(m1 - s_M[il + 32]) * s_inv[il + 32];
        const int swz = il & 3;
        float* base_a = s_acc + js * 1024;
#pragma unroll
        for (int q = 0; q < 4; ++q) {
            float4 v0, v1;
            v0.x = acc0[4*q+0] * k0; v0.y = acc0[4*q+1] * k0;
            v0.z = acc0[4*q+2] * k0; v0.w = acc0[4*q+3] * k0;
            v1.x = acc1[4*q+0] * k1; v1.y = acc1[4*q+1] * k1;
            v1.z = acc1[4*q+2] * k1; v1.w = acc1[4*q+3] * k1;
            *(float4*)(base_a + il * 16        + 4 * (q ^ swz)) = v0;
            *(float4*)(base_a + (il + 32) * 16 + 4 * (q ^ swz)) = v1;
        }
    }
    __syncthreads();

    {   // final reduce over 16 slices: thread (i = t>>4, f = t&15), 2 rows each
        const int i  = t >> 4;
        const int f  = t & 15;
        const int e  = f & 3, qf = f >> 2;
#pragma unroll
        for (int r = 0; r < 2; ++r) {
            const int lr = i + r * 32;
            const int w  = lr * 16 + 4 * (qf ^ (lr & 3)) + e;
            float o = 0.f;
#pragma unroll
            for (int k = 0; k < 16; ++k) o += s_acc[k * 1024 + w];
            const int grow = i0 + lr;
            if (Wout) {                  // fused h @ W_out partial per head
                float v = o * Wout[hh * NHID + f];
#pragma unroll
                for (int off = 8; off; off >>= 1) v += __shfl_xor(v, off);
                if (f == 0) atomicAdd(out + b * NN + grow, v);
            } else {
                hout[((size_t)(b * NN + grow)) * DH + hh * NHID + f] = o;
            }
        }
    }

    // layer 1 zeroes the atomic target for layer 2 (stream-ordered)
    if (lay == 1 && blk < 4) out[blk * 512 + t] = 0.f;
}

extern "C" void kernel_launch(void* const* d_in, const int* in_sizes, int n_in,
                              void* d_out, int out_size, void* d_ws, size_t ws_size,
                              hipStream_t stream) {
    const float* X    = (const float*)d_in[0];   // [4,512,2]
    const int*   adj  = (const int*)  d_in[1];   // [4,512,512]
    const float* Win  = (const float*)d_in[2];   // [2,128]
    const float* Wl   = (const float*)d_in[3];   // [3,128,128]
    const float* Wr   = (const float*)d_in[4];   // [3,128,128]
    const float* Aa   = (const float*)d_in[5];   // [3,16]
    const float* Wout = (const float*)d_in[6];   // [128,1]
    float* out = (float*)d_out;                  // [4,512] fp32

    float*    ws   = (float*)d_ws;
    float*    h_a  = ws;                         // 1 MB (layer-0 output)
    float*    h_b  = ws + 262144;                // 1 MB (layer-1 output)
    uint32_t* adjb = (uint32_t*)(ws + 524288);   // 128 KB

    gat_layer<<<256, 512, 0, stream>>>(0, X, nullptr, h_a, Win,
        Wl,               Wr,               Aa,      nullptr, out, adjb, adj);
    gat_layer<<<256, 512, 0, stream>>>(1, nullptr, h_a, h_b, Win,
        Wl + DH * DH,     Wr + DH * DH,     Aa + 16, nullptr, out, adjb, adj);
    gat_layer<<<256, 512, 0, stream>>>(2, nullptr, h_b, nullptr, Win,
        Wl + 2 * DH * DH, Wr + 2 * DH * DH, Aa + 32, Wout,    out, adjb, adj);
}

// Round 7
// 168.313 us; speedup vs baseline: 1.3210x; 1.3210x over previous
//
#include <hip/hip_runtime.h>
#include <cstdint>
#include <math.h>

#define NB 4
#define NN 512
#define DH 128
#define NHEADS 8
#define NHID 16
#define ITILE 64
#define SENTINEL -1e30f

// ---- fully-fused GAT layer v3: amortized-LDS proj + flash attention ----
// 3 dispatches total. Block (b, hh, it): 512 threads, 95.9 KB LDS, 1 block/CU.
//
// proj phase (rewritten this round; R6's scalar-pipe W was latency-bound):
//   Inter-layer activations are stored TRANSPOSED: hT[b][k][row]. Thread
//   (c4 = t>>7 col-octet, rq = t&127) computes rows 4rq..4rq+3 x 8 cols:
//   - h for its 4 rows per k = ONE coalesced global b128 (lanes contiguous,
//     L2-resident, VMEM pipe) -- no LDS h staging at all.
//   - W octet per k = 2 LDS b128 broadcasts amortized over 4 rows:
//     256/thread vs R5's 1024 (the ~17 us LDS storm).
//   Layer 0 needs no h input: h_k = x0*Win[0][k] + x1*Win[1][k] on the fly
//   (same summation order as reference -> exact).
//
// attn phase: byte-identical math to the verified R5 kernel (absmax 0.0).
// Layer 0 packs adj bitmasks; layer 1 zeroes out[]; layer 2 fuses @W_out.
__global__ __launch_bounds__(512, 1) void gat_layer(
    const int lay,
    const float* __restrict__ X,
    const float* __restrict__ hTin, float* __restrict__ hTout,
    const float* __restrict__ Win,
    const float* __restrict__ WlL, const float* __restrict__ WrL,
    const float* __restrict__ a_vec, const float* __restrict__ Wout,
    float* __restrict__ out, uint32_t* __restrict__ adjb,
    const int* __restrict__ adj)
{
    __shared__ __align__(16) float smem[23968];   // 95,872 B -> 1 block/CU
    float* s_W   = smem;                  // [128][32] cols 0-15 Wl, 16-31 Wr
    float* s_Win = smem + 4096;           // [2][128] (layer 0 only)
    float4* Sgl  = (float4*)(smem + 4352);   // [4][512] f-major gl chunks
    float4* Sgr  = (float4*)(smem + 12544);  // [4][512] f-major gr chunks
    float* s_dgl = smem + 20736;          // [512]
    float* s_dgr = smem + 21248;          // [512]
    float* s_m   = smem + 21760;          // [16][65]
    float* s_l   = smem + 22800;          // [16][65]
    float* s_M   = smem + 23840;          // [64]
    float* s_inv = smem + 23904;          // [64]
    float* s_acc = smem;                  // alias [16][64][16]: W/Win/Sgl/Sgr
                                          // region, all dead post-PV

    const int blk = blockIdx.x;           // 256 = ((b*8+hh)*8) + it
    const int it  = blk & 7;
    const int bh  = blk >> 3;
    const int b   = bh >> 3;
    const int hh  = bh & 7;
    const int i0  = it * ITILE;
    const int t   = threadIdx.x;
    const int il  = t & 31;
    const int js  = t >> 5;               // [0,16)
    const int r0  = i0 + il;
    const int r1  = r0 + 32;

    // ---- stage W head-slices -> s_W[k][32]; Win (layer 0) ----
    for (int c = t; c < 1024; c += 512) {
        const int k = c >> 3, j = c & 7;
        if (j < 4)
            *(float4*)&s_W[k * 32 + j * 4] =
                *(const float4*)&WlL[k * DH + hh * NHID + j * 4];
        else
            *(float4*)&s_W[k * 32 + 16 + (j - 4) * 4] =
                *(const float4*)&WrL[k * DH + hh * NHID + (j - 4) * 4];
    }
    if (lay == 0 && t < 64) ((float4*)s_Win)[t] = ((const float4*)Win)[t];

    float a[16];
#pragma unroll
    for (int q = 0; q < 4; ++q) {
        const float4 v = ((const float4*)a_vec)[q];
        a[4*q+0] = v.x; a[4*q+1] = v.y; a[4*q+2] = v.z; a[4*q+3] = v.w;
    }

    // ---- masks: layer 0 packs from adj (and stores for reuse); else load ----
    uint32_t mask0, mask1;
    if (lay == 0) {
        const int4* p0 = (const int4*)(adj + ((size_t)(b * NN + r0)) * NN + js * 32);
        const int4* p1 = (const int4*)(adj + ((size_t)(b * NN + r1)) * NN + js * 32);
        uint32_t m0 = 0, m1 = 0;
#pragma unroll
        for (int c = 0; c < 8; ++c) {
            const int4 v0 = p0[c], v1 = p1[c];
            m0 |= (v0.x != 0 ? 1u : 0u) << (c * 4 + 0);
            m0 |= (v0.y != 0 ? 1u : 0u) << (c * 4 + 1);
            m0 |= (v0.z != 0 ? 1u : 0u) << (c * 4 + 2);
            m0 |= (v0.w != 0 ? 1u : 0u) << (c * 4 + 3);
            m1 |= (v1.x != 0 ? 1u : 0u) << (c * 4 + 0);
            m1 |= (v1.y != 0 ? 1u : 0u) << (c * 4 + 1);
            m1 |= (v1.z != 0 ? 1u : 0u) << (c * 4 + 2);
            m1 |= (v1.w != 0 ? 1u : 0u) << (c * 4 + 3);
        }
        mask0 = m0; mask1 = m1;
        adjb[((size_t)(b * NN + r0)) * 16 + js] = m0;  // 8 hh-blocks same value: benign
        adjb[((size_t)(b * NN + r1)) * 16 + js] = m1;
    } else {
        mask0 = adjb[((size_t)(b * NN + r0)) * 16 + js];
        mask1 = adjb[((size_t)(b * NN + r1)) * 16 + js];
    }
    __syncthreads();                      // s_W/s_Win staged

    // ---- proj: thread (c4, rq) -> rows 4rq..4rq+3, cols c4*8..+7 ----
    {
        const int c4 = t >> 7;            // wave-uniform (2 waves per c4)
        const int rq = t & 127;
        const float* wcol = s_W + ((c4 >> 1) * 16 + (c4 & 1) * 8);
        float acc[4][8];
#pragma unroll
        for (int m = 0; m < 4; ++m)
#pragma unroll
            for (int c = 0; c < 8; ++c) acc[m][c] = 0.f;

        if (lay == 0) {
            const float4 xa = *(const float4*)&X[(size_t)(b * NN + 4 * rq) * 2];
            const float4 xb = *(const float4*)&X[(size_t)(b * NN + 4 * rq) * 2 + 4];
            const float x0[4] = {xa.x, xa.z, xb.x, xb.z};
            const float x1[4] = {xa.y, xa.w, xb.y, xb.w};
#pragma unroll 2
            for (int kq = 0; kq < 32; ++kq) {
                const float4 w0 = *(const float4*)&s_Win[kq * 4];
                const float4 w1 = *(const float4*)&s_Win[128 + kq * 4];
                const float w0a[4] = {w0.x, w0.y, w0.z, w0.w};
                const float w1a[4] = {w1.x, w1.y, w1.z, w1.w};
#pragma unroll
                for (int kk = 0; kk < 4; ++kk) {
                    const int k = kq * 4 + kk;
                    const float4 wa = *(const float4*)&wcol[k * 32];
                    const float4 wb = *(const float4*)&wcol[k * 32 + 4];
#pragma unroll
                    for (int m = 0; m < 4; ++m) {
                        const float hm = x0[m] * w0a[kk] + x1[m] * w1a[kk];
                        acc[m][0] = fmaf(hm, wa.x, acc[m][0]);
                        acc[m][1] = fmaf(hm, wa.y, acc[m][1]);
                        acc[m][2] = fmaf(hm, wa.z, acc[m][2]);
                        acc[m][3] = fmaf(hm, wa.w, acc[m][3]);
                        acc[m][4] = fmaf(hm, wb.x, acc[m][4]);
                        acc[m][5] = fmaf(hm, wb.y, acc[m][5]);
                        acc[m][6] = fmaf(hm, wb.z, acc[m][6]);
                        acc[m][7] = fmaf(hm, wb.w, acc[m][7]);
                    }
                }
            }
        } else {
            const float* hT = hTin + (size_t)b * DH * NN;   // [128][512]
#pragma unroll 2
            for (int k = 0; k < DH; ++k) {
                const float4 h4 = *(const float4*)&hT[k * NN + 4 * rq]; // coalesced
                const float4 wa = *(const float4*)&wcol[k * 32];        // broadcast
                const float4 wb = *(const float4*)&wcol[k * 32 + 4];
                const float hm4[4] = {h4.x, h4.y, h4.z, h4.w};
#pragma unroll
                for (int m = 0; m < 4; ++m) {
                    const float hm = hm4[m];
                    acc[m][0] = fmaf(hm, wa.x, acc[m][0]);
                    acc[m][1] = fmaf(hm, wa.y, acc[m][1]);
                    acc[m][2] = fmaf(hm, wa.z, acc[m][2]);
                    acc[m][3] = fmaf(hm, wa.w, acc[m][3]);
                    acc[m][4] = fmaf(hm, wb.x, acc[m][4]);
                    acc[m][5] = fmaf(hm, wb.y, acc[m][5]);
                    acc[m][6] = fmaf(hm, wb.z, acc[m][6]);
                    acc[m][7] = fmaf(hm, wb.w, acc[m][7]);
                }
            }
        }
        // write f-major plane slices
        float4* Sg = (c4 < 2) ? Sgl : Sgr;
        const int q0 = (c4 & 1) * 2;
#pragma unroll
        for (int m = 0; m < 4; ++m) {
            float4 v0, v1;
            v0.x = acc[m][0]; v0.y = acc[m][1]; v0.z = acc[m][2]; v0.w = acc[m][3];
            v1.x = acc[m][4]; v1.y = acc[m][5]; v1.z = acc[m][6]; v1.w = acc[m][7];
            Sg[q0 * 512       + 4 * rq + m] = v0;
            Sg[(q0 + 1) * 512 + 4 * rq + m] = v1;
        }
    }
    __syncthreads();                      // planes complete

    {   // dgl[t] = a . gl[t], dgr[t] = a . gr[t] (lane-consecutive reads)
        float dl = 0.f, dr = 0.f;
#pragma unroll
        for (int q = 0; q < 4; ++q) {
            const float4 vl = Sgl[q * 512 + t];
            const float4 vr = Sgr[q * 512 + t];
            dl = fmaf(a[4*q+0], vl.x, dl); dl = fmaf(a[4*q+1], vl.y, dl);
            dl = fmaf(a[4*q+2], vl.z, dl); dl = fmaf(a[4*q+3], vl.w, dl);
            dr = fmaf(a[4*q+0], vr.x, dr); dr = fmaf(a[4*q+1], vr.y, dr);
            dr = fmaf(a[4*q+2], vr.z, dr); dr = fmaf(a[4*q+3], vr.w, dr);
        }
        s_dgl[t] = dl;
        s_dgr[t] = dr;
    }
    __syncthreads();                      // dgl/dgr ready

    // ---- gri for own 2 rows ----
    float gri0[16], gri1[16];
#pragma unroll
    for (int q = 0; q < 4; ++q) {
        const float4 v0 = Sgr[q * 512 + r0];
        const float4 v1 = Sgr[q * 512 + r1];
        gri0[4*q+0] = v0.x; gri0[4*q+1] = v0.y; gri0[4*q+2] = v0.z; gri0[4*q+3] = v0.w;
        gri1[4*q+0] = v1.x; gri1[4*q+1] = v1.y; gri1[4*q+2] = v1.z; gri1[4*q+3] = v1.w;
    }

    // ---- pass 1: scores for 2 rows x 32 j ----
    const float c0 = 0.6f * s_dgr[r0];
    const float c1 = 0.6f * s_dgr[r1];
    const int jbase = js * 32;
    float sc0[32], sc1[32];
#pragma unroll
    for (int jj = 0; jj < 32; ++jj) {
        const int j = jbase + jj;
        const float dj = s_dgl[j];
        float s0 = 0.f, s1 = 0.f;
#pragma unroll
        for (int q = 0; q < 4; ++q) {
            const float4 g = Sgl[q * 512 + j];   // uniform j -> broadcast
            float v;
            v = g.x + gri0[4*q+0]; s0 = fmaf(a[4*q+0], fabsf(v), s0);
            v = g.y + gri0[4*q+1]; s0 = fmaf(a[4*q+1], fabsf(v), s0);
            v = g.z + gri0[4*q+2]; s0 = fmaf(a[4*q+2], fabsf(v), s0);
            v = g.w + gri0[4*q+3]; s0 = fmaf(a[4*q+3], fabsf(v), s0);
            v = g.x + gri1[4*q+0]; s1 = fmaf(a[4*q+0], fabsf(v), s1);
            v = g.y + gri1[4*q+1]; s1 = fmaf(a[4*q+1], fabsf(v), s1);
            v = g.z + gri1[4*q+2]; s1 = fmaf(a[4*q+2], fabsf(v), s1);
            v = g.w + gri1[4*q+3]; s1 = fmaf(a[4*q+3], fabsf(v), s1);
        }
        const float b0 = fmaf(0.6f, dj, c0);
        const float b1 = fmaf(0.6f, dj, c1);
        sc0[jj] = ((mask0 >> jj) & 1u) ? fmaf(0.4f, s0, b0) : SENTINEL;
        sc1[jj] = ((mask1 >> jj) & 1u) ? fmaf(0.4f, s1, b1) : SENTINEL;
    }

    // ---- in-register softmax (two-pass) ----
    float m0 = sc0[0], m1 = sc1[0];
#pragma unroll
    for (int jj = 1; jj < 32; ++jj) { m0 = fmaxf(m0, sc0[jj]); m1 = fmaxf(m1, sc1[jj]); }
    float l0 = 0.f, l1 = 0.f;
#pragma unroll
    for (int jj = 0; jj < 32; ++jj) {
        sc0[jj] = __expf(sc0[jj] - m0); l0 += sc0[jj];
        sc1[jj] = __expf(sc1[jj] - m1); l1 += sc1[jj];
    }
    s_m[js * 65 + il]      = m0;
    s_m[js * 65 + il + 32] = m1;
    s_l[js * 65 + il]      = l0;
    s_l[js * 65 + il + 32] = l1;

    // ---- pass 2: PV aggregation ----
    float acc0[16], acc1[16];
#pragma unroll
    for (int f = 0; f < 16; ++f) { acc0[f] = 0.f; acc1[f] = 0.f; }
#pragma unroll
    for (int jj = 0; jj < 32; ++jj) {
        const int j = jbase + jj;
        const float p0 = sc0[jj], p1 = sc1[jj];
#pragma unroll
        for (int q = 0; q < 4; ++q) {
            const float4 g = Sgr[q * 512 + j];   // broadcast
            acc0[4*q+0] = fmaf(p0, g.x, acc0[4*q+0]);
            acc0[4*q+1] = fmaf(p0, g.y, acc0[4*q+1]);
            acc0[4*q+2] = fmaf(p0, g.z, acc0[4*q+2]);
            acc0[4*q+3] = fmaf(p0, g.w, acc0[4*q+3]);
            acc1[4*q+0] = fmaf(p1, g.x, acc1[4*q+0]);
            acc1[4*q+1] = fmaf(p1, g.y, acc1[4*q+1]);
            acc1[4*q+2] = fmaf(p1, g.z, acc1[4*q+2]);
            acc1[4*q+3] = fmaf(p1, g.w, acc1[4*q+3]);
        }
    }
    __syncthreads();                      // retires plane reads + s_m/s_l writes

    if (t < 64) {                         // per-row global max + denom over 16 slices
        float M = SENTINEL;
#pragma unroll
        for (int k = 0; k < 16; ++k) M = fmaxf(M, s_m[k * 65 + t]);
        float L = 0.f;
#pragma unroll
        for (int k = 0; k < 16; ++k) L += s_l[k * 65 + t] * __expf(s_m[k * 65 + t] - M);
        s_M[t]   = M;
        s_inv[t] = 1.f / L;
    }
    __syncthreads();

    {   // scaled partials into aliased scratch; chunk-XOR swizzle
        const float k0 = __expf(m0 - s_M[il])      * s_inv[il];
        const float k1 = __expf(m1 - s_M[il + 32]) * s_inv[il + 32];
        const int swz = il & 3;
        float* base_a = s_acc + js * 1024;
#pragma unroll
        for (int q = 0; q < 4; ++q) {
            float4 v0, v1;
            v0.x = acc0[4*q+0] * k0; v0.y = acc0[4*q+1] * k0;
            v0.z = acc0[4*q+2] * k0; v0.w = acc0[4*q+3] * k0;
            v1.x = acc1[4*q+0] * k1; v1.y = acc1[4*q+1] * k1;
            v1.z = acc1[4*q+2] * k1; v1.w = acc1[4*q+3] * k1;
            *(float4*)(base_a + il * 16        + 4 * (q ^ swz)) = v0;
            *(float4*)(base_a + (il + 32) * 16 + 4 * (q ^ swz)) = v1;
        }
    }
    __syncthreads();

    {   // final reduce over 16 slices: thread (i = t>>4, f = t&15), 2 rows each
        const int i  = t >> 4;
        const int f  = t & 15;
        const int e  = f & 3, qf = f >> 2;
#pragma unroll
        for (int r = 0; r < 2; ++r) {
            const int lr = i + r * 32;
            const int w  = lr * 16 + 4 * (qf ^ (lr & 3)) + e;
            float o = 0.f;
#pragma unroll
            for (int k = 0; k < 16; ++k) o += s_acc[k * 1024 + w];
            const int grow = i0 + lr;
            if (Wout) {                   // fused h @ W_out partial per head
                float v = o * Wout[hh * NHID + f];
#pragma unroll
                for (int off = 8; off; off >>= 1) v += __shfl_xor(v, off);
                if (f == 0) atomicAdd(out + b * NN + grow, v);
            } else {                      // transposed activation for next layer
                hTout[((size_t)b * DH + hh * NHID + f) * NN + grow] = o;
            }
        }
    }

    // layer 1 zeroes the atomic target for layer 2 (stream-ordered)
    if (lay == 1 && blk < 4) out[blk * 512 + t] = 0.f;
}

extern "C" void kernel_launch(void* const* d_in, const int* in_sizes, int n_in,
                              void* d_out, int out_size, void* d_ws, size_t ws_size,
                              hipStream_t stream) {
    const float* X    = (const float*)d_in[0];   // [4,512,2]
    const int*   adj  = (const int*)  d_in[1];   // [4,512,512]
    const float* Win  = (const float*)d_in[2];   // [2,128]
    const float* Wl   = (const float*)d_in[3];   // [3,128,128]
    const float* Wr   = (const float*)d_in[4];   // [3,128,128]
    const float* Aa   = (const float*)d_in[5];   // [3,16]
    const float* Wout = (const float*)d_in[6];   // [128,1]
    float* out = (float*)d_out;                  // [4,512] fp32

    float*    ws   = (float*)d_ws;
    float*    hT_a = ws;                         // 1 MB, [4][128][512]
    float*    hT_b = ws + 262144;                // 1 MB
    uint32_t* adjb = (uint32_t*)(ws + 524288);   // 128 KB

    gat_layer<<<256, 512, 0, stream>>>(0, X, nullptr, hT_a, Win,
        Wl,               Wr,               Aa,      nullptr, out, adjb, adj);
    gat_layer<<<256, 512, 0, stream>>>(1, nullptr, hT_a, hT_b, Win,
        Wl + DH * DH,     Wr + DH * DH,     Aa + 16, nullptr, out, adjb, adj);
    gat_layer<<<256, 512, 0, stream>>>(2, nullptr, hT_b, nullptr, Win,
        Wl + 2 * DH * DH, Wr + 2 * DH * DH, Aa + 32, Wout,    out, adjb, adj);
}

// Round 8
// 160.383 us; speedup vs baseline: 1.3863x; 1.0494x over previous
//
#include <hip/hip_runtime.h>
#include <cstdint>
#include <math.h>

#define NB 4
#define NN 512
#define DH 128
#define NHEADS 8
#define NHID 16
#define ITILE 64
#define SENTINEL -1e30f

// ---- fully-fused GAT layer v4: latency-batched proj + flash attention ----
// 3 dispatches total. Block (b, hh, it): 512 threads, 95.9 KB LDS, 1 block/CU.
//
// proj phase: thread (c4 = t>>7 col-octet, rq = t&127) computes rows
// 4rq..4rq+3 x 8 cols. hT[b][k][row] reads are BATCHED 16-deep into a
// statically-indexed register array (R7 read them one-at-a-time in a
// dependent chain -> ~300cy x 128 iters of L2 latency; VALUBusy 55%).
// 16 independent global_load_dwordx4 in flight per batch amortizes the
// latency 16x. W octets come from LDS broadcasts (2 b128/k, amortized x4
// rows). Layer 0 rebuilds h_k = x0*Win[0][k]+x1*Win[1][k] on the fly (exact).
//
// attn phase: byte-identical math to the verified R5/R7 kernel (absmax 0.0).
// Layer 0 packs adj bitmasks; layer 1 zeroes out[]; layer 2 fuses @W_out.
__global__ __launch_bounds__(512, 1) void gat_layer(
    const int lay,
    const float* __restrict__ X,
    const float* __restrict__ hTin, float* __restrict__ hTout,
    const float* __restrict__ Win,
    const float* __restrict__ WlL, const float* __restrict__ WrL,
    const float* __restrict__ a_vec, const float* __restrict__ Wout,
    float* __restrict__ out, uint32_t* __restrict__ adjb,
    const int* __restrict__ adj)
{
    __shared__ __align__(16) float smem[23968];   // 95,872 B -> 1 block/CU
    float* s_W   = smem;                  // [128][32] cols 0-15 Wl, 16-31 Wr
    float* s_Win = smem + 4096;           // [2][128] (layer 0 only)
    float4* Sgl  = (float4*)(smem + 4352);   // [4][512] f-major gl chunks
    float4* Sgr  = (float4*)(smem + 12544);  // [4][512] f-major gr chunks
    float* s_dgl = smem + 20736;          // [512]
    float* s_dgr = smem + 21248;          // [512]
    float* s_m   = smem + 21760;          // [16][65]
    float* s_l   = smem + 22800;          // [16][65]
    float* s_M   = smem + 23840;          // [64]
    float* s_inv = smem + 23904;          // [64]
    float* s_acc = smem;                  // alias [16][64][16]: W/Win/Sgl/Sgr
                                          // region, all dead post-PV

    const int blk = blockIdx.x;           // 256 = ((b*8+hh)*8) + it
    const int it  = blk & 7;
    const int bh  = blk >> 3;
    const int b   = bh >> 3;
    const int hh  = bh & 7;
    const int i0  = it * ITILE;
    const int t   = threadIdx.x;
    const int il  = t & 31;
    const int js  = t >> 5;               // [0,16)
    const int r0  = i0 + il;
    const int r1  = r0 + 32;

    // ---- stage W head-slices -> s_W[k][32]; Win (layer 0) ----
    for (int c = t; c < 1024; c += 512) {
        const int k = c >> 3, j = c & 7;
        if (j < 4)
            *(float4*)&s_W[k * 32 + j * 4] =
                *(const float4*)&WlL[k * DH + hh * NHID + j * 4];
        else
            *(float4*)&s_W[k * 32 + 16 + (j - 4) * 4] =
                *(const float4*)&WrL[k * DH + hh * NHID + (j - 4) * 4];
    }
    if (lay == 0 && t < 64) ((float4*)s_Win)[t] = ((const float4*)Win)[t];

    float a[16];
#pragma unroll
    for (int q = 0; q < 4; ++q) {
        const float4 v = ((const float4*)a_vec)[q];
        a[4*q+0] = v.x; a[4*q+1] = v.y; a[4*q+2] = v.z; a[4*q+3] = v.w;
    }

    // ---- masks: layer 0 packs from adj (and stores for reuse); else load ----
    uint32_t mask0, mask1;
    if (lay == 0) {
        const int4* p0 = (const int4*)(adj + ((size_t)(b * NN + r0)) * NN + js * 32);
        const int4* p1 = (const int4*)(adj + ((size_t)(b * NN + r1)) * NN + js * 32);
        uint32_t m0 = 0, m1 = 0;
#pragma unroll
        for (int c = 0; c < 8; ++c) {
            const int4 v0 = p0[c], v1 = p1[c];
            m0 |= (v0.x != 0 ? 1u : 0u) << (c * 4 + 0);
            m0 |= (v0.y != 0 ? 1u : 0u) << (c * 4 + 1);
            m0 |= (v0.z != 0 ? 1u : 0u) << (c * 4 + 2);
            m0 |= (v0.w != 0 ? 1u : 0u) << (c * 4 + 3);
            m1 |= (v1.x != 0 ? 1u : 0u) << (c * 4 + 0);
            m1 |= (v1.y != 0 ? 1u : 0u) << (c * 4 + 1);
            m1 |= (v1.z != 0 ? 1u : 0u) << (c * 4 + 2);
            m1 |= (v1.w != 0 ? 1u : 0u) << (c * 4 + 3);
        }
        mask0 = m0; mask1 = m1;
        adjb[((size_t)(b * NN + r0)) * 16 + js] = m0;  // 8 hh-blocks same value: benign
        adjb[((size_t)(b * NN + r1)) * 16 + js] = m1;
    } else {
        mask0 = adjb[((size_t)(b * NN + r0)) * 16 + js];
        mask1 = adjb[((size_t)(b * NN + r1)) * 16 + js];
    }
    __syncthreads();                      // s_W/s_Win staged

    // ---- proj: thread (c4, rq) -> rows 4rq..4rq+3, cols c4*8..+7 ----
    {
        const int c4 = t >> 7;            // wave-uniform (2 waves per c4)
        const int rq = t & 127;
        const float* wcol = s_W + ((c4 >> 1) * 16 + (c4 & 1) * 8);
        float acc[4][8];
#pragma unroll
        for (int m = 0; m < 4; ++m)
#pragma unroll
            for (int c = 0; c < 8; ++c) acc[m][c] = 0.f;

        if (lay == 0) {
            const float4 xa = *(const float4*)&X[(size_t)(b * NN + 4 * rq) * 2];
            const float4 xb = *(const float4*)&X[(size_t)(b * NN + 4 * rq) * 2 + 4];
            const float x0[4] = {xa.x, xa.z, xb.x, xb.z};
            const float x1[4] = {xa.y, xa.w, xb.y, xb.w};
#pragma unroll 2
            for (int kq = 0; kq < 32; ++kq) {
                const float4 w0 = *(const float4*)&s_Win[kq * 4];
                const float4 w1 = *(const float4*)&s_Win[128 + kq * 4];
                const float w0a[4] = {w0.x, w0.y, w0.z, w0.w};
                const float w1a[4] = {w1.x, w1.y, w1.z, w1.w};
#pragma unroll
                for (int kk = 0; kk < 4; ++kk) {
                    const int k = kq * 4 + kk;
                    const float4 wa = *(const float4*)&wcol[k * 32];
                    const float4 wb = *(const float4*)&wcol[k * 32 + 4];
#pragma unroll
                    for (int m = 0; m < 4; ++m) {
                        const float hm = x0[m] * w0a[kk] + x1[m] * w1a[kk];
                        acc[m][0] = fmaf(hm, wa.x, acc[m][0]);
                        acc[m][1] = fmaf(hm, wa.y, acc[m][1]);
                        acc[m][2] = fmaf(hm, wa.z, acc[m][2]);
                        acc[m][3] = fmaf(hm, wa.w, acc[m][3]);
                        acc[m][4] = fmaf(hm, wb.x, acc[m][4]);
                        acc[m][5] = fmaf(hm, wb.y, acc[m][5]);
                        acc[m][6] = fmaf(hm, wb.z, acc[m][6]);
                        acc[m][7] = fmaf(hm, wb.w, acc[m][7]);
                    }
                }
            }
        } else {
            const float* hT = hTin + (size_t)b * DH * NN + 4 * rq;   // [128][512]
#pragma unroll 1
            for (int kb = 0; kb < DH; kb += 16) {
                // 16 independent coalesced loads issued back-to-back:
                // latency amortized 16x (R7 had a 1-deep dependent chain)
                float4 hb[16];
#pragma unroll
                for (int u = 0; u < 16; ++u)
                    hb[u] = *(const float4*)&hT[(size_t)(kb + u) * NN];
#pragma unroll
                for (int u = 0; u < 16; ++u) {
                    const int k = kb + u;
                    const float4 wa = *(const float4*)&wcol[k * 32];  // broadcast
                    const float4 wb = *(const float4*)&wcol[k * 32 + 4];
                    const float hm4[4] = {hb[u].x, hb[u].y, hb[u].z, hb[u].w};
#pragma unroll
                    for (int m = 0; m < 4; ++m) {
                        const float hm = hm4[m];
                        acc[m][0] = fmaf(hm, wa.x, acc[m][0]);
                        acc[m][1] = fmaf(hm, wa.y, acc[m][1]);
                        acc[m][2] = fmaf(hm, wa.z, acc[m][2]);
                        acc[m][3] = fmaf(hm, wa.w, acc[m][3]);
                        acc[m][4] = fmaf(hm, wb.x, acc[m][4]);
                        acc[m][5] = fmaf(hm, wb.y, acc[m][5]);
                        acc[m][6] = fmaf(hm, wb.z, acc[m][6]);
                        acc[m][7] = fmaf(hm, wb.w, acc[m][7]);
                    }
                }
            }
        }
        // write f-major plane slices
        float4* Sg = (c4 < 2) ? Sgl : Sgr;
        const int q0 = (c4 & 1) * 2;
#pragma unroll
        for (int m = 0; m < 4; ++m) {
            float4 v0, v1;
            v0.x = acc[m][0]; v0.y = acc[m][1]; v0.z = acc[m][2]; v0.w = acc[m][3];
            v1.x = acc[m][4]; v1.y = acc[m][5]; v1.z = acc[m][6]; v1.w = acc[m][7];
            Sg[q0 * 512       + 4 * rq + m] = v0;
            Sg[(q0 + 1) * 512 + 4 * rq + m] = v1;
        }
    }
    __syncthreads();                      // planes complete

    {   // dgl[t] = a . gl[t], dgr[t] = a . gr[t] (lane-consecutive reads)
        float dl = 0.f, dr = 0.f;
#pragma unroll
        for (int q = 0; q < 4; ++q) {
            const float4 vl = Sgl[q * 512 + t];
            const float4 vr = Sgr[q * 512 + t];
            dl = fmaf(a[4*q+0], vl.x, dl); dl = fmaf(a[4*q+1], vl.y, dl);
            dl = fmaf(a[4*q+2], vl.z, dl); dl = fmaf(a[4*q+3], vl.w, dl);
            dr = fmaf(a[4*q+0], vr.x, dr); dr = fmaf(a[4*q+1], vr.y, dr);
            dr = fmaf(a[4*q+2], vr.z, dr); dr = fmaf(a[4*q+3], vr.w, dr);
        }
        s_dgl[t] = dl;
        s_dgr[t] = dr;
    }
    __syncthreads();                      // dgl/dgr ready

    // ---- gri for own 2 rows ----
    float gri0[16], gri1[16];
#pragma unroll
    for (int q = 0; q < 4; ++q) {
        const float4 v0 = Sgr[q * 512 + r0];
        const float4 v1 = Sgr[q * 512 + r1];
        gri0[4*q+0] = v0.x; gri0[4*q+1] = v0.y; gri0[4*q+2] = v0.z; gri0[4*q+3] = v0.w;
        gri1[4*q+0] = v1.x; gri1[4*q+1] = v1.y; gri1[4*q+2] = v1.z; gri1[4*q+3] = v1.w;
    }

    // ---- pass 1: scores for 2 rows x 32 j ----
    const float c0 = 0.6f * s_dgr[r0];
    const float c1 = 0.6f * s_dgr[r1];
    const int jbase = js * 32;
    float sc0[32], sc1[32];
#pragma unroll
    for (int jj = 0; jj < 32; ++jj) {
        const int j = jbase + jj;
        const float dj = s_dgl[j];
        float s0 = 0.f, s1 = 0.f;
#pragma unroll
        for (int q = 0; q < 4; ++q) {
            const float4 g = Sgl[q * 512 + j];   // uniform j -> broadcast
            float v;
            v = g.x + gri0[4*q+0]; s0 = fmaf(a[4*q+0], fabsf(v), s0);
            v = g.y + gri0[4*q+1]; s0 = fmaf(a[4*q+1], fabsf(v), s0);
            v = g.z + gri0[4*q+2]; s0 = fmaf(a[4*q+2], fabsf(v), s0);
            v = g.w + gri0[4*q+3]; s0 = fmaf(a[4*q+3], fabsf(v), s0);
            v = g.x + gri1[4*q+0]; s1 = fmaf(a[4*q+0], fabsf(v), s1);
            v = g.y + gri1[4*q+1]; s1 = fmaf(a[4*q+1], fabsf(v), s1);
            v = g.z + gri1[4*q+2]; s1 = fmaf(a[4*q+2], fabsf(v), s1);
            v = g.w + gri1[4*q+3]; s1 = fmaf(a[4*q+3], fabsf(v), s1);
        }
        const float b0 = fmaf(0.6f, dj, c0);
        const float b1 = fmaf(0.6f, dj, c1);
        sc0[jj] = ((mask0 >> jj) & 1u) ? fmaf(0.4f, s0, b0) : SENTINEL;
        sc1[jj] = ((mask1 >> jj) & 1u) ? fmaf(0.4f, s1, b1) : SENTINEL;
    }

    // ---- in-register softmax (two-pass) ----
    float m0 = sc0[0], m1 = sc1[0];
#pragma unroll
    for (int jj = 1; jj < 32; ++jj) { m0 = fmaxf(m0, sc0[jj]); m1 = fmaxf(m1, sc1[jj]); }
    float l0 = 0.f, l1 = 0.f;
#pragma unroll
    for (int jj = 0; jj < 32; ++jj) {
        sc0[jj] = __expf(sc0[jj] - m0); l0 += sc0[jj];
        sc1[jj] = __expf(sc1[jj] - m1); l1 += sc1[jj];
    }
    s_m[js * 65 + il]      = m0;
    s_m[js * 65 + il + 32] = m1;
    s_l[js * 65 + il]      = l0;
    s_l[js * 65 + il + 32] = l1;

    // ---- pass 2: PV aggregation ----
    float acc0[16], acc1[16];
#pragma unroll
    for (int f = 0; f < 16; ++f) { acc0[f] = 0.f; acc1[f] = 0.f; }
#pragma unroll
    for (int jj = 0; jj < 32; ++jj) {
        const int j = jbase + jj;
        const float p0 = sc0[jj], p1 = sc1[jj];
#pragma unroll
        for (int q = 0; q < 4; ++q) {
            const float4 g = Sgr[q * 512 + j];   // broadcast
            acc0[4*q+0] = fmaf(p0, g.x, acc0[4*q+0]);
            acc0[4*q+1] = fmaf(p0, g.y, acc0[4*q+1]);
            acc0[4*q+2] = fmaf(p0, g.z, acc0[4*q+2]);
            acc0[4*q+3] = fmaf(p0, g.w, acc0[4*q+3]);
            acc1[4*q+0] = fmaf(p1, g.x, acc1[4*q+0]);
            acc1[4*q+1] = fmaf(p1, g.y, acc1[4*q+1]);
            acc1[4*q+2] = fmaf(p1, g.z, acc1[4*q+2]);
            acc1[4*q+3] = fmaf(p1, g.w, acc1[4*q+3]);
        }
    }
    __syncthreads();                      // retires plane reads + s_m/s_l writes

    if (t < 64) {                         // per-row global max + denom over 16 slices
        float M = SENTINEL;
#pragma unroll
        for (int k = 0; k < 16; ++k) M = fmaxf(M, s_m[k * 65 + t]);
        float L = 0.f;
#pragma unroll
        for (int k = 0; k < 16; ++k) L += s_l[k * 65 + t] * __expf(s_m[k * 65 + t] - M);
        s_M[t]   = M;
        s_inv[t] = 1.f / L;
    }
    __syncthreads();

    {   // scaled partials into aliased scratch; chunk-XOR swizzle
        const float k0 = __expf(m0 - s_M[il])      * s_inv[il];
        const float k1 = __expf(m1 - s_M[il + 32]) * s_inv[il + 32];
        const int swz = il & 3;
        float* base_a = s_acc + js * 1024;
#pragma unroll
        for (int q = 0; q < 4; ++q) {
            float4 v0, v1;
            v0.x = acc0[4*q+0] * k0; v0.y = acc0[4*q+1] * k0;
            v0.z = acc0[4*q+2] * k0; v0.w = acc0[4*q+3] * k0;
            v1.x = acc1[4*q+0] * k1; v1.y = acc1[4*q+1] * k1;
            v1.z = acc1[4*q+2] * k1; v1.w = acc1[4*q+3] * k1;
            *(float4*)(base_a + il * 16        + 4 * (q ^ swz)) = v0;
            *(float4*)(base_a + (il + 32) * 16 + 4 * (q ^ swz)) = v1;
        }
    }
    __syncthreads();

    {   // final reduce over 16 slices: thread (i = t>>4, f = t&15), 2 rows each
        const int i  = t >> 4;
        const int f  = t & 15;
        const int e  = f & 3, qf = f >> 2;
#pragma unroll
        for (int r = 0; r < 2; ++r) {
            const int lr = i + r * 32;
            const int w  = lr * 16 + 4 * (qf ^ (lr & 3)) + e;
            float o = 0.f;
#pragma unroll
            for (int k = 0; k < 16; ++k) o += s_acc[k * 1024 + w];
            const int grow = i0 + lr;
            if (Wout) {                   // fused h @ W_out partial per head
                float v = o * Wout[hh * NHID + f];
#pragma unroll
                for (int off = 8; off; off >>= 1) v += __shfl_xor(v, off);
                if (f == 0) atomicAdd(out + b * NN + grow, v);
            } else {                      // transposed activation for next layer
                hTout[((size_t)b * DH + hh * NHID + f) * NN + grow] = o;
            }
        }
    }

    // layer 1 zeroes the atomic target for layer 2 (stream-ordered)
    if (lay == 1 && blk < 4) out[blk * 512 + t] = 0.f;
}

extern "C" void kernel_launch(void* const* d_in, const int* in_sizes, int n_in,
                              void* d_out, int out_size, void* d_ws, size_t ws_size,
                              hipStream_t stream) {
    const float* X    = (const float*)d_in[0];   // [4,512,2]
    const int*   adj  = (const int*)  d_in[1];   // [4,512,512]
    const float* Win  = (const float*)d_in[2];   // [2,128]
    const float* Wl   = (const float*)d_in[3];   // [3,128,128]
    const float* Wr   = (const float*)d_in[4];   // [3,128,128]
    const float* Aa   = (const float*)d_in[5];   // [3,16]
    const float* Wout = (const float*)d_in[6];   // [128,1]
    float* out = (float*)d_out;                  // [4,512] fp32

    float*    ws   = (float*)d_ws;
    float*    hT_a = ws;                         // 1 MB, [4][128][512]
    float*    hT_b = ws + 262144;                // 1 MB
    uint32_t* adjb = (uint32_t*)(ws + 524288);   // 128 KB

    gat_layer<<<256, 512, 0, stream>>>(0, X, nullptr, hT_a, Win,
        Wl,               Wr,               Aa,      nullptr, out, adjb, adj);
    gat_layer<<<256, 512, 0, stream>>>(1, nullptr, hT_a, hT_b, Win,
        Wl + DH * DH,     Wr + DH * DH,     Aa + 16, nullptr, out, adjb, adj);
    gat_layer<<<256, 512, 0, stream>>>(2, nullptr, hT_b, nullptr, Win,
        Wl + 2 * DH * DH, Wr + 2 * DH * DH, Aa + 32, Wout,    out, adjb, adj);
}

// Round 9
// 155.001 us; speedup vs baseline: 1.4344x; 1.0347x over previous
//
#include <hip/hip_runtime.h>
#include <cstdint>
#include <math.h>

#define NB 4
#define NN 512
#define DH 128
#define NHEADS 8
#define NHID 16
#define ITILE 64
#define SENTINEL -1e30f

// ---- packed-f32 helpers (VOP3P, gfx90a+): 2 IEEE f32 ops per instr ----
typedef __attribute__((ext_vector_type(2))) float f32x2;

// d = a*b + c (both halves), b.lo broadcast to both halves
__device__ __forceinline__ f32x2 pk_fma_blo(f32x2 a, f32x2 b, f32x2 c) {
    f32x2 d;
    asm("v_pk_fma_f32 %0, %1, %2, %3 op_sel_hi:[1,0,1]"
        : "=v"(d) : "v"(a), "v"(b), "v"(c));
    return d;
}
// d = a*b + c (both halves), b.hi broadcast to both halves
__device__ __forceinline__ f32x2 pk_fma_bhi(f32x2 a, f32x2 b, f32x2 c) {
    f32x2 d;
    asm("v_pk_fma_f32 %0, %1, %2, %3 op_sel:[0,1,0] op_sel_hi:[1,1,1]"
        : "=v"(d) : "v"(a), "v"(b), "v"(c));
    return d;
}
__device__ __forceinline__ f32x2 pk_add(f32x2 a, f32x2 b) {
    f32x2 d;
    asm("v_pk_add_f32 %0, %1, %2" : "=v"(d) : "v"(a), "v"(b));
    return d;
}

// ---- fully-fused GAT layer v5: packed-f32 proj/score/PV + flash attention ----
// 3 dispatches total. Block (b, hh, it): 512 threads, 95.9 KB LDS, 1 block/CU.
// R8 analysis: kernel is VALU-instruction-issue-bound (~8.6K scalar VALU/thread).
// This round packs the three FMA-dense loops with v_pk_fma_f32 / v_pk_add_f32
// (op_sel broadcasts -> zero mov overhead). Per-element op order preserved ->
// bit-identical results (absmax 0.0). All else identical to verified R8.
__global__ __launch_bounds__(512, 1) void gat_layer(
    const int lay,
    const float* __restrict__ X,
    const float* __restrict__ hTin, float* __restrict__ hTout,
    const float* __restrict__ Win,
    const float* __restrict__ WlL, const float* __restrict__ WrL,
    const float* __restrict__ a_vec, const float* __restrict__ Wout,
    float* __restrict__ out, uint32_t* __restrict__ adjb,
    const int* __restrict__ adj)
{
    __shared__ __align__(16) float smem[23968];   // 95,872 B -> 1 block/CU
    float* s_W   = smem;                  // [128][32] cols 0-15 Wl, 16-31 Wr
    float* s_Win = smem + 4096;           // [2][128] (layer 0 only)
    float4* Sgl  = (float4*)(smem + 4352);   // [4][512] f-major gl chunks
    float4* Sgr  = (float4*)(smem + 12544);  // [4][512] f-major gr chunks
    float* s_dgl = smem + 20736;          // [512]
    float* s_dgr = smem + 21248;          // [512]
    float* s_m   = smem + 21760;          // [16][65]
    float* s_l   = smem + 22800;          // [16][65]
    float* s_M   = smem + 23840;          // [64]
    float* s_inv = smem + 23904;          // [64]
    float* s_acc = smem;                  // alias [16][64][16], dead post-PV

    const int blk = blockIdx.x;           // 256 = ((b*8+hh)*8) + it
    const int it  = blk & 7;
    const int bh  = blk >> 3;
    const int b   = bh >> 3;
    const int hh  = bh & 7;
    const int i0  = it * ITILE;
    const int t   = threadIdx.x;
    const int il  = t & 31;
    const int js  = t >> 5;               // [0,16)
    const int r0  = i0 + il;
    const int r1  = r0 + 32;

    // ---- stage W head-slices -> s_W[k][32]; Win (layer 0) ----
    for (int c = t; c < 1024; c += 512) {
        const int k = c >> 3, j = c & 7;
        if (j < 4)
            *(float4*)&s_W[k * 32 + j * 4] =
                *(const float4*)&WlL[k * DH + hh * NHID + j * 4];
        else
            *(float4*)&s_W[k * 32 + 16 + (j - 4) * 4] =
                *(const float4*)&WrL[k * DH + hh * NHID + (j - 4) * 4];
    }
    if (lay == 0 && t < 64) ((float4*)s_Win)[t] = ((const float4*)Win)[t];

    float a[16];
#pragma unroll
    for (int q = 0; q < 4; ++q) {
        const float4 v = ((const float4*)a_vec)[q];
        a[4*q+0] = v.x; a[4*q+1] = v.y; a[4*q+2] = v.z; a[4*q+3] = v.w;
    }

    // ---- masks: layer 0 packs from adj (and stores for reuse); else load ----
    uint32_t mask0, mask1;
    if (lay == 0) {
        const int4* p0 = (const int4*)(adj + ((size_t)(b * NN + r0)) * NN + js * 32);
        const int4* p1 = (const int4*)(adj + ((size_t)(b * NN + r1)) * NN + js * 32);
        uint32_t m0 = 0, m1 = 0;
#pragma unroll
        for (int c = 0; c < 8; ++c) {
            const int4 v0 = p0[c], v1 = p1[c];
            m0 |= (v0.x != 0 ? 1u : 0u) << (c * 4 + 0);
            m0 |= (v0.y != 0 ? 1u : 0u) << (c * 4 + 1);
            m0 |= (v0.z != 0 ? 1u : 0u) << (c * 4 + 2);
            m0 |= (v0.w != 0 ? 1u : 0u) << (c * 4 + 3);
            m1 |= (v1.x != 0 ? 1u : 0u) << (c * 4 + 0);
            m1 |= (v1.y != 0 ? 1u : 0u) << (c * 4 + 1);
            m1 |= (v1.z != 0 ? 1u : 0u) << (c * 4 + 2);
            m1 |= (v1.w != 0 ? 1u : 0u) << (c * 4 + 3);
        }
        mask0 = m0; mask1 = m1;
        adjb[((size_t)(b * NN + r0)) * 16 + js] = m0;  // 8 hh-blocks same value: benign
        adjb[((size_t)(b * NN + r1)) * 16 + js] = m1;
    } else {
        mask0 = adjb[((size_t)(b * NN + r0)) * 16 + js];
        mask1 = adjb[((size_t)(b * NN + r1)) * 16 + js];
    }
    __syncthreads();                      // s_W/s_Win staged

    // ---- proj: thread (c4, rq) -> rows 4rq..4rq+3, cols c4*8..+7 ----
    {
        const int c4 = t >> 7;            // wave-uniform (2 waves per c4)
        const int rq = t & 127;
        const float* wcol = s_W + ((c4 >> 1) * 16 + (c4 & 1) * 8);
        f32x2 acc2[4][4];                 // [row][colpair]
#pragma unroll
        for (int m = 0; m < 4; ++m)
#pragma unroll
            for (int c = 0; c < 4; ++c) acc2[m][c] = (f32x2){0.f, 0.f};

        if (lay == 0) {
            const float4 xa = *(const float4*)&X[(size_t)(b * NN + 4 * rq) * 2];
            const float4 xb = *(const float4*)&X[(size_t)(b * NN + 4 * rq) * 2 + 4];
            const float x0[4] = {xa.x, xa.z, xb.x, xb.z};
            const float x1[4] = {xa.y, xa.w, xb.y, xb.w};
#pragma unroll 2
            for (int kq = 0; kq < 32; ++kq) {
                const float4 w0 = *(const float4*)&s_Win[kq * 4];
                const float4 w1 = *(const float4*)&s_Win[128 + kq * 4];
                const float w0a[4] = {w0.x, w0.y, w0.z, w0.w};
                const float w1a[4] = {w1.x, w1.y, w1.z, w1.w};
#pragma unroll
                for (int kk = 0; kk < 4; ++kk) {
                    const int k = kq * 4 + kk;
                    const float4 wa = *(const float4*)&wcol[k * 32];
                    const float4 wb = *(const float4*)&wcol[k * 32 + 4];
                    const f32x2 W0 = {wa.x, wa.y}, W1 = {wa.z, wa.w};
                    const f32x2 W2 = {wb.x, wb.y}, W3 = {wb.z, wb.w};
                    const float hm0 = x0[0] * w0a[kk] + x1[0] * w1a[kk];
                    const float hm1 = x0[1] * w0a[kk] + x1[1] * w1a[kk];
                    const float hm2 = x0[2] * w0a[kk] + x1[2] * w1a[kk];
                    const float hm3 = x0[3] * w0a[kk] + x1[3] * w1a[kk];
                    const f32x2 H0 = {hm0, hm1}, H1 = {hm2, hm3};
                    acc2[0][0] = pk_fma_blo(W0, H0, acc2[0][0]);
                    acc2[0][1] = pk_fma_blo(W1, H0, acc2[0][1]);
                    acc2[0][2] = pk_fma_blo(W2, H0, acc2[0][2]);
                    acc2[0][3] = pk_fma_blo(W3, H0, acc2[0][3]);
                    acc2[1][0] = pk_fma_bhi(W0, H0, acc2[1][0]);
                    acc2[1][1] = pk_fma_bhi(W1, H0, acc2[1][1]);
                    acc2[1][2] = pk_fma_bhi(W2, H0, acc2[1][2]);
                    acc2[1][3] = pk_fma_bhi(W3, H0, acc2[1][3]);
                    acc2[2][0] = pk_fma_blo(W0, H1, acc2[2][0]);
                    acc2[2][1] = pk_fma_blo(W1, H1, acc2[2][1]);
                    acc2[2][2] = pk_fma_blo(W2, H1, acc2[2][2]);
                    acc2[2][3] = pk_fma_blo(W3, H1, acc2[2][3]);
                    acc2[3][0] = pk_fma_bhi(W0, H1, acc2[3][0]);
                    acc2[3][1] = pk_fma_bhi(W1, H1, acc2[3][1]);
                    acc2[3][2] = pk_fma_bhi(W2, H1, acc2[3][2]);
                    acc2[3][3] = pk_fma_bhi(W3, H1, acc2[3][3]);
                }
            }
        } else {
            const float* hT = hTin + (size_t)b * DH * NN + 4 * rq;   // [128][512]
#pragma unroll 1
            for (int kb = 0; kb < DH; kb += 16) {
                float4 hb[16];            // 16 independent loads in flight
#pragma unroll
                for (int u = 0; u < 16; ++u)
                    hb[u] = *(const float4*)&hT[(size_t)(kb + u) * NN];
#pragma unroll
                for (int u = 0; u < 16; ++u) {
                    const int k = kb + u;
                    const float4 wa = *(const float4*)&wcol[k * 32];  // broadcast
                    const float4 wb = *(const float4*)&wcol[k * 32 + 4];
                    const f32x2 W0 = {wa.x, wa.y}, W1 = {wa.z, wa.w};
                    const f32x2 W2 = {wb.x, wb.y}, W3 = {wb.z, wb.w};
                    const f32x2 H0 = {hb[u].x, hb[u].y}, H1 = {hb[u].z, hb[u].w};
                    acc2[0][0] = pk_fma_blo(W0, H0, acc2[0][0]);
                    acc2[0][1] = pk_fma_blo(W1, H0, acc2[0][1]);
                    acc2[0][2] = pk_fma_blo(W2, H0, acc2[0][2]);
                    acc2[0][3] = pk_fma_blo(W3, H0, acc2[0][3]);
                    acc2[1][0] = pk_fma_bhi(W0, H0, acc2[1][0]);
                    acc2[1][1] = pk_fma_bhi(W1, H0, acc2[1][1]);
                    acc2[1][2] = pk_fma_bhi(W2, H0, acc2[1][2]);
                    acc2[1][3] = pk_fma_bhi(W3, H0, acc2[1][3]);
                    acc2[2][0] = pk_fma_blo(W0, H1, acc2[2][0]);
                    acc2[2][1] = pk_fma_blo(W1, H1, acc2[2][1]);
                    acc2[2][2] = pk_fma_blo(W2, H1, acc2[2][2]);
                    acc2[2][3] = pk_fma_blo(W3, H1, acc2[2][3]);
                    acc2[3][0] = pk_fma_bhi(W0, H1, acc2[3][0]);
                    acc2[3][1] = pk_fma_bhi(W1, H1, acc2[3][1]);
                    acc2[3][2] = pk_fma_bhi(W2, H1, acc2[3][2]);
                    acc2[3][3] = pk_fma_bhi(W3, H1, acc2[3][3]);
                }
            }
        }
        // write f-major plane slices
        float4* Sg = (c4 < 2) ? Sgl : Sgr;
        const int q0 = (c4 & 1) * 2;
#pragma unroll
        for (int m = 0; m < 4; ++m) {
            float4 v0, v1;
            v0.x = acc2[m][0].x; v0.y = acc2[m][0].y;
            v0.z = acc2[m][1].x; v0.w = acc2[m][1].y;
            v1.x = acc2[m][2].x; v1.y = acc2[m][2].y;
            v1.z = acc2[m][3].x; v1.w = acc2[m][3].y;
            Sg[q0 * 512       + 4 * rq + m] = v0;
            Sg[(q0 + 1) * 512 + 4 * rq + m] = v1;
        }
    }
    __syncthreads();                      // planes complete

    {   // dgl[t] = a . gl[t], dgr[t] = a . gr[t] (lane-consecutive reads)
        float dl = 0.f, dr = 0.f;
#pragma unroll
        for (int q = 0; q < 4; ++q) {
            const float4 vl = Sgl[q * 512 + t];
            const float4 vr = Sgr[q * 512 + t];
            dl = fmaf(a[4*q+0], vl.x, dl); dl = fmaf(a[4*q+1], vl.y, dl);
            dl = fmaf(a[4*q+2], vl.z, dl); dl = fmaf(a[4*q+3], vl.w, dl);
            dr = fmaf(a[4*q+0], vr.x, dr); dr = fmaf(a[4*q+1], vr.y, dr);
            dr = fmaf(a[4*q+2], vr.z, dr); dr = fmaf(a[4*q+3], vr.w, dr);
        }
        s_dgl[t] = dl;
        s_dgr[t] = dr;
    }
    __syncthreads();                      // dgl/dgr ready

    // ---- gri for own 2 rows (as f32x2 pairs) ----
    f32x2 gri0p[8], gri1p[8];
#pragma unroll
    for (int q = 0; q < 4; ++q) {
        const float4 v0 = Sgr[q * 512 + r0];
        const float4 v1 = Sgr[q * 512 + r1];
        gri0p[2*q+0] = (f32x2){v0.x, v0.y}; gri0p[2*q+1] = (f32x2){v0.z, v0.w};
        gri1p[2*q+0] = (f32x2){v1.x, v1.y}; gri1p[2*q+1] = (f32x2){v1.z, v1.w};
    }

    // ---- pass 1: scores for 2 rows x 32 j (pk_add + scalar |.| fma) ----
    const float c0 = 0.6f * s_dgr[r0];
    const float c1 = 0.6f * s_dgr[r1];
    const int jbase = js * 32;
    float sc0[32], sc1[32];
#pragma unroll
    for (int jj = 0; jj < 32; ++jj) {
        const int j = jbase + jj;
        const float dj = s_dgl[j];
        float s0 = 0.f, s1 = 0.f;
#pragma unroll
        for (int q = 0; q < 4; ++q) {
            const float4 g = Sgl[q * 512 + j];   // uniform j -> broadcast
            const f32x2 Ga = {g.x, g.y}, Gb = {g.z, g.w};
            const f32x2 v0a = pk_add(Ga, gri0p[2*q+0]);
            const f32x2 v0b = pk_add(Gb, gri0p[2*q+1]);
            const f32x2 v1a = pk_add(Ga, gri1p[2*q+0]);
            const f32x2 v1b = pk_add(Gb, gri1p[2*q+1]);
            s0 = fmaf(a[4*q+0], fabsf(v0a.x), s0);
            s0 = fmaf(a[4*q+1], fabsf(v0a.y), s0);
            s0 = fmaf(a[4*q+2], fabsf(v0b.x), s0);
            s0 = fmaf(a[4*q+3], fabsf(v0b.y), s0);
            s1 = fmaf(a[4*q+0], fabsf(v1a.x), s1);
            s1 = fmaf(a[4*q+1], fabsf(v1a.y), s1);
            s1 = fmaf(a[4*q+2], fabsf(v1b.x), s1);
            s1 = fmaf(a[4*q+3], fabsf(v1b.y), s1);
        }
        const float b0 = fmaf(0.6f, dj, c0);
        const float b1 = fmaf(0.6f, dj, c1);
        sc0[jj] = ((mask0 >> jj) & 1u) ? fmaf(0.4f, s0, b0) : SENTINEL;
        sc1[jj] = ((mask1 >> jj) & 1u) ? fmaf(0.4f, s1, b1) : SENTINEL;
    }

    // ---- in-register softmax (two-pass) ----
    float m0 = sc0[0], m1 = sc1[0];
#pragma unroll
    for (int jj = 1; jj < 32; ++jj) { m0 = fmaxf(m0, sc0[jj]); m1 = fmaxf(m1, sc1[jj]); }
    float l0 = 0.f, l1 = 0.f;
#pragma unroll
    for (int jj = 0; jj < 32; ++jj) {
        sc0[jj] = __expf(sc0[jj] - m0); l0 += sc0[jj];
        sc1[jj] = __expf(sc1[jj] - m1); l1 += sc1[jj];
    }
    s_m[js * 65 + il]      = m0;
    s_m[js * 65 + il + 32] = m1;
    s_l[js * 65 + il]      = l0;
    s_l[js * 65 + il + 32] = l1;

    // ---- pass 2: PV aggregation (packed, {p0,p1} op_sel broadcast) ----
    f32x2 acc0p[8], acc1p[8];
#pragma unroll
    for (int f = 0; f < 8; ++f) { acc0p[f] = (f32x2){0.f, 0.f}; acc1p[f] = (f32x2){0.f, 0.f}; }
#pragma unroll
    for (int jj = 0; jj < 32; ++jj) {
        const int j = jbase + jj;
        const f32x2 pp = {sc0[jj], sc1[jj]};
#pragma unroll
        for (int q = 0; q < 4; ++q) {
            const float4 g = Sgr[q * 512 + j];   // broadcast
            const f32x2 Ga = {g.x, g.y}, Gb = {g.z, g.w};
            acc0p[2*q+0] = pk_fma_blo(Ga, pp, acc0p[2*q+0]);
            acc0p[2*q+1] = pk_fma_blo(Gb, pp, acc0p[2*q+1]);
            acc1p[2*q+0] = pk_fma_bhi(Ga, pp, acc1p[2*q+0]);
            acc1p[2*q+1] = pk_fma_bhi(Gb, pp, acc1p[2*q+1]);
        }
    }
    __syncthreads();                      // retires plane reads + s_m/s_l writes

    if (t < 64) {                         // per-row global max + denom over 16 slices
        float M = SENTINEL;
#pragma unroll
        for (int k = 0; k < 16; ++k) M = fmaxf(M, s_m[k * 65 + t]);
        float L = 0.f;
#pragma unroll
        for (int k = 0; k < 16; ++k) L += s_l[k * 65 + t] * __expf(s_m[k * 65 + t] - M);
        s_M[t]   = M;
        s_inv[t] = 1.f / L;
    }
    __syncthreads();

    {   // scaled partials into aliased scratch; chunk-XOR swizzle
        const float k0 = __expf(m0 - s_M[il])      * s_inv[il];
        const float k1 = __expf(m1 - s_M[il + 32]) * s_inv[il + 32];
        const int swz = il & 3;
        float* base_a = s_acc + js * 1024;
#pragma unroll
        for (int q = 0; q < 4; ++q) {
            float4 v0, v1;
            v0.x = acc0p[2*q+0].x * k0; v0.y = acc0p[2*q+0].y * k0;
            v0.z = acc0p[2*q+1].x * k0; v0.w = acc0p[2*q+1].y * k0;
            v1.x = acc1p[2*q+0].x * k1; v1.y = acc1p[2*q+0].y * k1;
            v1.z = acc1p[2*q+1].x * k1; v1.w = acc1p[2*q+1].y * k1;
            *(float4*)(base_a + il * 16        + 4 * (q ^ swz)) = v0;
            *(float4*)(base_a + (il + 32) * 16 + 4 * (q ^ swz)) = v1;
        }
    }
    __syncthreads();

    {   // final reduce over 16 slices: thread (i = t>>4, f = t&15), 2 rows each
        const int i  = t >> 4;
        const int f  = t & 15;
        const int e  = f & 3, qf = f >> 2;
#pragma unroll
        for (int r = 0; r < 2; ++r) {
            const int lr = i + r * 32;
            const int w  = lr * 16 + 4 * (qf ^ (lr & 3)) + e;
            float o = 0.f;
#pragma unroll
            for (int k = 0; k < 16; ++k) o += s_acc[k * 1024 + w];
            const int grow = i0 + lr;
            if (Wout) {                   // fused h @ W_out partial per head
                float v = o * Wout[hh * NHID + f];
#pragma unroll
                for (int off = 8; off; off >>= 1) v += __shfl_xor(v, off);
                if (f == 0) atomicAdd(out + b * NN + grow, v);
            } else {                      // transposed activation for next layer
                hTout[((size_t)b * DH + hh * NHID + f) * NN + grow] = o;
            }
        }
    }

    // layer 1 zeroes the atomic target for layer 2 (stream-ordered)
    if (lay == 1 && blk < 4) out[blk * 512 + t] = 0.f;
}

extern "C" void kernel_launch(void* const* d_in, const int* in_sizes, int n_in,
                              void* d_out, int out_size, void* d_ws, size_t ws_size,
                              hipStream_t stream) {
    const float* X    = (const float*)d_in[0];   // [4,512,2]
    const int*   adj  = (const int*)  d_in[1];   // [4,512,512]
    const float* Win  = (const float*)d_in[2];   // [2,128]
    const float* Wl   = (const float*)d_in[3];   // [3,128,128]
    const float* Wr   = (const float*)d_in[4];   // [3,128,128]
    const float* Aa   = (const float*)d_in[5];   // [3,16]
    const float* Wout = (const float*)d_in[6];   // [128,1]
    float* out = (float*)d_out;                  // [4,512] fp32

    float*    ws   = (float*)d_ws;
    float*    hT_a = ws;                         // 1 MB, [4][128][512]
    float*    hT_b = ws + 262144;                // 1 MB
    uint32_t* adjb = (uint32_t*)(ws + 524288);   // 128 KB

    gat_layer<<<256, 512, 0, stream>>>(0, X, nullptr, hT_a, Win,
        Wl,               Wr,               Aa,      nullptr, out, adjb, adj);
    gat_layer<<<256, 512, 0, stream>>>(1, nullptr, hT_a, hT_b, Win,
        Wl + DH * DH,     Wr + DH * DH,     Aa + 16, nullptr, out, adjb, adj);
    gat_layer<<<256, 512, 0, stream>>>(2, nullptr, hT_b, nullptr, Win,
        Wl + 2 * DH * DH, Wr + 2 * DH * DH, Aa + 32, Wout,    out, adjb, adj);
}